// Round 4
// baseline (238.946 us; speedup 1.0000x reference)
//
#include <hip/hip_runtime.h>

#define B_   16
#define C_   128
#define HW_  16384

typedef __attribute__((ext_vector_type(4))) float  floatx4;
typedef __attribute__((ext_vector_type(8))) short  short8;
typedef __attribute__((ext_vector_type(4))) short  short4v;

static __device__ __forceinline__ unsigned short f2bf(float f){
  unsigned int u = __float_as_uint(f);
  u += 0x7FFFu + ((u >> 16) & 1u);
  return (unsigned short)(u >> 16);
}
static __device__ __forceinline__ float bf2f(unsigned short h){
  return __uint_as_float(((unsigned int)h) << 16);
}
static __device__ __forceinline__ float elu1(float v){
  return v > 0.f ? v + 1.f : __expf(v);
}
// xT swizzle key (period 128 in n, so 128-row half-tiles keep the same key)
static __device__ __forceinline__ int keyx(int n){ return ((n >> 1) & 7) ^ ((n >> 4) & 7); }

// ---- K1: x -> xT (bf16, tile-major [b][tile256][n][c] pre-swizzled LDS image) + GN1 partial stats ----
__global__ __launch_bounds__(512) void k_xprep(const float* __restrict__ x,
    unsigned short* __restrict__ xT, float* __restrict__ gn1part){
  int blk = blockIdx.x;                        // b*64 + tile
  int b = blk >> 6, tile = blk & 63;
  int n0 = tile * 256;
  __shared__ unsigned short XS[32768];
  int t = threadIdx.x, w = t >> 6, l = t & 63;
  float sk[4], sk2[4];
  #pragma unroll
  for (int k = 0; k < 4; ++k){ sk[k] = 0.f; sk2[k] = 0.f; }
  #pragma unroll
  for (int k = 0; k < 4; ++k){
    float4 f4[4];
    #pragma unroll
    for (int j = 0; j < 4; ++j){
      int c = 16*w + 4*k + j;
      f4[j] = *(const float4*)(x + ((size_t)(b*128 + c))*HW_ + n0 + 4*l);
    }
    #pragma unroll
    for (int j = 0; j < 4; ++j){
      sk[k]  += f4[j].x + f4[j].y + f4[j].z + f4[j].w;
      sk2[k] += f4[j].x*f4[j].x + f4[j].y*f4[j].y + f4[j].z*f4[j].z + f4[j].w*f4[j].w;
    }
    int c0 = 16*w + 4*k, cs = c0 >> 3, co = c0 & 7;
    #pragma unroll
    for (int i = 0; i < 4; ++i){
      int n = 4*l + i;
      short4v p;
      #pragma unroll
      for (int j = 0; j < 4; ++j) p[j] = (short)f2bf(((const float*)&f4[j])[i]);
      *(short4v*)(XS + n*128 + (((cs ^ keyx(n)) << 3) + co)) = p;
    }
  }
  #pragma unroll
  for (int k = 0; k < 4; ++k){
    float a = sk[k], q = sk2[k];
    #pragma unroll
    for (int o = 32; o; o >>= 1){ a += __shfl_down(a, o); q += __shfl_down(q, o); }
    if (l == 0){
      gn1part[((size_t)blk)*64 + (4*w + k)*2 + 0] = a;
      gn1part[((size_t)blk)*64 + (4*w + k)*2 + 1] = q;
    }
  }
  __syncthreads();
  unsigned short* dst = xT + ((size_t)blk)*32768;
  for (int it = 0; it < 8; ++it){
    int slot = t + it*512;
    *(short8*)(dst + slot*8) = *(const short8*)(XS + slot*8);
  }
}

// ---- K1f: finalize GN1 stats ----
__global__ __launch_bounds__(64) void k_gn1fin(const float* __restrict__ gn1part,
    float* __restrict__ mean, float* __restrict__ rstd){
  int bg = blockIdx.x;
  int b = bg >> 5, g = bg & 31, l = threadIdx.x;
  const float* p = gn1part + ((size_t)(b*64 + l))*64 + g*2;
  float s = p[0], s2 = p[1];
  #pragma unroll
  for (int o = 32; o; o >>= 1){ s += __shfl_down(s, o); s2 += __shfl_down(s2, o); }
  if (l == 0){
    float m = s * (1.f/65536.f);
    float var = s2 * (1.f/65536.f) - m*m;
    mean[bg] = m; rstd[bg] = rsqrtf(var + 1e-5f);
  }
}

// ---- K2: fold GN1 into qkv weights (per batch), w_out -> bf16 ----
__global__ __launch_bounds__(64) void k_fold(const float* __restrict__ wqkv, const float* __restrict__ wout,
    const float* __restrict__ g1w, const float* __restrict__ g1b,
    const float* __restrict__ mean, const float* __restrict__ rstd,
    unsigned short* __restrict__ wqp, float* __restrict__ bias, unsigned short* __restrict__ woutb){
  int i = blockIdx.x, l = threadIdx.x;
  if (i < 6144){
    int b = i / 384, o = i % 384;
    float bsum = 0.f;
    #pragma unroll
    for (int j = 0; j < 2; ++j){
      int c = l*2 + j, g = c >> 2;
      float m = mean[b*32 + g], r = rstd[b*32 + g];
      float A  = r * g1w[c];
      float Bc = g1b[c] - m * A;
      float wv = wqkv[o*128 + c];
      wqp[((size_t)(b*384 + o))*128 + c] = f2bf(wv * A);
      bsum += wv * Bc;
    }
    #pragma unroll
    for (int o2 = 32; o2; o2 >>= 1) bsum += __shfl_down(bsum, o2);
    if (l == 0) bias[b*384 + o] = bsum;
  } else {
    int r = i - 6144;
    #pragma unroll
    for (int j = 0; j < 2; ++j){ int c = l*2 + j; woutb[r*128 + c] = f2bf(wout[r*128 + c]); }
  }
}

// ---- K3: k,v GEMM (4rt x 4ct per wave) + VGPR-accumulated kv/ksum over 8 sub-tiles ----
__global__ __launch_bounds__(512) void k_kv(const unsigned short* __restrict__ xT,
    const unsigned short* __restrict__ wqp, const float* __restrict__ bias,
    float* __restrict__ kvpart, float* __restrict__ ksumpart){
  int blk = blockIdx.x;                        // b*16 + chunk; chunk = 4 tiles of 256 n
  int b = blk >> 4, chunk = blk & 15;
  __shared__ unsigned short S[32768];          // 32KB x/k image + 32KB v image
  int t = threadIdx.x, w = t >> 6, lane = t & 63, lr = lane & 15, lk = lane >> 4;
  int rg = w >> 1, cg = w & 1;                 // rg: 4 row-groups of 4 tiles; cg: 2 col-groups of 4
  short8 afr[4][4]; float biasr[4][4];
  #pragma unroll
  for (int rtl = 0; rtl < 4; ++rtl){
    int o = 128 + (rg*4 + rtl)*16;
    #pragma unroll
    for (int ks = 0; ks < 4; ++ks)
      afr[rtl][ks] = *(const short8*)(wqp + ((size_t)(b*384 + o + lr))*128 + ks*32 + lk*8);
    #pragma unroll
    for (int r = 0; r < 4; ++r) biasr[rtl][r] = bias[b*384 + o + lk*4 + r];
  }
  short8 ones;
  #pragma unroll
  for (int j = 0; j < 8; ++j) ones[j] = (short)0x3F80;
  floatx4 accA = {0,0,0,0}, accB = {0,0,0,0}, ksaA = {0,0,0,0}, ksaB = {0,0,0,0};
  for (int it = 0; it < 8; ++it){
    const unsigned short* src = xT + ((size_t)(b*64 + chunk*4 + (it>>1)))*32768 + (it&1)*16384;
    #pragma unroll
    for (int i = 0; i < 4; ++i){
      int slot = t + i*512;
      *(short8*)(S + slot*8) = *(const short8*)(src + slot*8);
    }
    __syncthreads();
    short4v pk[4][4];
    #pragma unroll
    for (int ctl = 0; ctl < 4; ++ctl){
      int nr = (cg*4 + ctl)*16 + lr;
      int kn = keyx(nr);
      short8 bfr[4];
      #pragma unroll
      for (int ks = 0; ks < 4; ++ks)
        bfr[ks] = *(const short8*)(S + nr*128 + (((ks*4 + lk) ^ kn) << 3));
      #pragma unroll
      for (int rtl = 0; rtl < 4; ++rtl){
        floatx4 acc = {0.f,0.f,0.f,0.f};
        #pragma unroll
        for (int ks = 0; ks < 4; ++ks)
          acc = __builtin_amdgcn_mfma_f32_16x16x32_bf16(afr[rtl][ks], bfr[ks], acc, 0,0,0);
        #pragma unroll
        for (int r = 0; r < 4; ++r){
          float v = acc[r] + biasr[rtl][r];
          if (rg < 2) v = elu1(v);             // k rows get elu+1
          pk[rtl][ctl][r] = (short)f2bf(v);
        }
      }
    }
    __syncthreads();
    // build k/v images [128 c][128 n], key=(c>>1)&7  (k at 0, v at 16384)
    #pragma unroll
    for (int rtl = 0; rtl < 4; ++rtl){
      int rt = rg*4 + rtl;
      int cbase = (rt & 7)*16 + lk*4;
      int voff = (rt < 8) ? 0 : 16384;
      #pragma unroll
      for (int ctl = 0; ctl < 4; ++ctl){
        int n = (cg*4 + ctl)*16 + lr;
        #pragma unroll
        for (int r = 0; r < 4; ++r){
          int c = cbase + r;
          S[voff + c*128 + ((((n >> 3) ^ ((c >> 1) & 7)) << 3) + (n & 7))] = (unsigned short)pk[rtl][ctl][r];
        }
      }
    }
    __syncthreads();
    #pragma unroll
    for (int j = 0; j < 2; ++j){
      int m = w + 8*j;                         // 16 tasks: h x dt x et
      int h = m >> 2, dt = (m >> 1) & 1, et = m & 1;
      int arow = h*32 + dt*16 + lr, brow = h*32 + et*16 + lr;
      int akey = (lr >> 1) & 7;
      #pragma unroll
      for (int ks = 0; ks < 4; ++ks){
        short8 ka = *(const short8*)(S + arow*128 + (((ks*4 + lk) ^ akey) << 3));
        short8 vb = *(const short8*)(S + 16384 + brow*128 + (((ks*4 + lk) ^ akey) << 3));
        if (j == 0){
          accA = __builtin_amdgcn_mfma_f32_16x16x32_bf16(ka, vb, accA, 0,0,0);
          if (et == 0) ksaA = __builtin_amdgcn_mfma_f32_16x16x32_bf16(ka, ones, ksaA, 0,0,0);
        } else {
          accB = __builtin_amdgcn_mfma_f32_16x16x32_bf16(ka, vb, accB, 0,0,0);
          if (et == 0) ksaB = __builtin_amdgcn_mfma_f32_16x16x32_bf16(ka, ones, ksaB, 0,0,0);
        }
      }
    }
    __syncthreads();
  }
  #pragma unroll
  for (int j = 0; j < 2; ++j){
    int m = w + 8*j;
    int h = m >> 2, dt = (m >> 1) & 1, et = m & 1;
    floatx4 acc = j ? accB : accA, ksa = j ? ksaB : ksaA;
    float* kvp = kvpart + ((size_t)((b*16 + chunk)*4 + h))*1024;
    #pragma unroll
    for (int r = 0; r < 4; ++r)
      kvp[(dt*16 + lk*4 + r)*32 + et*16 + lr] = acc[r];
    if (et == 0 && lr == 0){
      float* ksp = ksumpart + ((size_t)((b*16 + chunk)*4 + h))*32;
      #pragma unroll
      for (int r = 0; r < 4; ++r) ksp[dt*16 + lk*4 + r] = ksa[r];
    }
  }
}

// ---- K3f: reduce kv/ksum partials, emit bf16 MFMA A-fragments ----
__global__ __launch_bounds__(256) void k_kvfin(const float* __restrict__ kvpart, const float* __restrict__ ksumpart,
    unsigned short* __restrict__ kvF){
  int bh = blockIdx.x, t = threadIdx.x;        // 64 = (b, h)
  int b = bh >> 2, h = bh & 3;
  __shared__ float kvL[1024];
  __shared__ float ksumL[32];
  for (int i = t; i < 1024; i += 256){
    float s = 0.f;
    for (int nt = 0; nt < 16; ++nt) s += kvpart[((size_t)((b*16 + nt)*4 + h))*1024 + i];
    kvL[i] = s;
  }
  if (t < 32){
    float s = 0.f;
    for (int nt = 0; nt < 16; ++nt) s += ksumpart[((size_t)((b*16 + nt)*4 + h))*32 + t];
    ksumL[t] = s;
  }
  __syncthreads();
  for (int idx = t; idx < 3*512; idx += 256){
    int f = idx >> 9, rem = idx & 511;
    int lane = rem >> 3, j = rem & 7;
    int d = (lane >> 4)*8 + j;
    float v = (f < 2) ? kvL[d*32 + f*16 + (lane & 15)] : ksumL[d];
    kvF[(size_t)(bh*3 + f)*512 + rem] = f2bf(v);
  }
}

// ---- K4: q GEMM (4x4 tiled) -> attention (MFMA) -> w_out GEMM (4x4 tiled) -> h(bf16) + GN2 partials ----
__global__ __launch_bounds__(512) void k_attn2(const unsigned short* __restrict__ xT,
    const unsigned short* __restrict__ wqp, const float* __restrict__ bias,
    const unsigned short* __restrict__ kvF, const unsigned short* __restrict__ woutb,
    unsigned short* __restrict__ hb, float* __restrict__ gn2part){
  int blk = blockIdx.x;                        // b*64 + tile256
  int b = blk >> 6;
  int n0 = (blk & 63) * 256;
  __shared__ unsigned short S[32768];          // xTile then aS [256 n][128 c] (key n&7)
  __shared__ float gnS[4][128][2];
  int t = threadIdx.x, w = t >> 6, lane = t & 63, lr = lane & 15, lk = lane >> 4;
  int rg = w >> 2, cg = w & 3;                 // rg: 2 row-groups of 4 tiles; cg: 4 col-groups of 4
  const unsigned short* src = xT + ((size_t)blk)*32768;
  for (int it = 0; it < 8; ++it){
    int slot = t + it*512;
    *(short8*)(S + slot*8) = *(const short8*)(src + slot*8);
  }
  short8 afr[4][4]; float biasq[4][4];
  #pragma unroll
  for (int rtl = 0; rtl < 4; ++rtl){
    int o = rg*64 + rtl*16;
    #pragma unroll
    for (int ks = 0; ks < 4; ++ks)
      afr[rtl][ks] = *(const short8*)(wqp + ((size_t)(b*384 + o + lr))*128 + ks*32 + lk*8);
    #pragma unroll
    for (int r = 0; r < 4; ++r) biasq[rtl][r] = bias[b*384 + o + lk*4 + r];
  }
  __syncthreads();
  // q-GEMM 4rt x 4ct
  short4v qpk[4][4];
  #pragma unroll
  for (int ctl = 0; ctl < 4; ++ctl){
    int nr = (cg*4 + ctl)*16 + lr;
    int kn = keyx(nr);
    short8 bfr[4];
    #pragma unroll
    for (int ks = 0; ks < 4; ++ks)
      bfr[ks] = *(const short8*)(S + nr*128 + (((ks*4 + lk) ^ kn) << 3));
    #pragma unroll
    for (int rtl = 0; rtl < 4; ++rtl){
      floatx4 acc = {0.f,0.f,0.f,0.f};
      #pragma unroll
      for (int ks = 0; ks < 4; ++ks)
        acc = __builtin_amdgcn_mfma_f32_16x16x32_bf16(afr[rtl][ks], bfr[ks], acc, 0,0,0);
      #pragma unroll
      for (int r = 0; r < 4; ++r) qpk[rtl][ctl][r] = (short)f2bf(elu1(acc[r] + biasq[rtl][r]));
    }
  }
  __syncthreads();
  // write q into aS [n][c], key = n&7
  #pragma unroll
  for (int rtl = 0; rtl < 4; ++rtl){
    int c0 = rg*64 + rtl*16 + lk*4;
    #pragma unroll
    for (int ctl = 0; ctl < 4; ++ctl){
      int n = (cg*4 + ctl)*16 + lr;
      *(short4v*)(S + n*128 + ((((c0 >> 3) ^ (n & 7)) << 3) + (c0 & 7))) = qpk[rtl][ctl];
    }
  }
  const unsigned short* kvFb = kvF + (size_t)b * 12 * 512;
  short8 kvf[4][2], ksf[4];
  #pragma unroll
  for (int h = 0; h < 4; ++h){
    kvf[h][0] = *(const short8*)(kvFb + (h*3 + 0)*512 + lane*8);
    kvf[h][1] = *(const short8*)(kvFb + (h*3 + 1)*512 + lane*8);
    ksf[h]    = *(const short8*)(kvFb + (h*3 + 2)*512 + lane*8);
  }
  __syncthreads();
  // attention: wave w owns n-rows 32w..32w+31
  short8 qf[2][4];
  #pragma unroll
  for (int nt = 0; nt < 2; ++nt){
    int n = w*32 + nt*16 + lr;
    #pragma unroll
    for (int h = 0; h < 4; ++h)
      qf[nt][h] = *(const short8*)(S + n*128 + (((4*h + lk) ^ (n & 7)) << 3));
  }
  #pragma unroll
  for (int nt = 0; nt < 2; ++nt){
    int n_local = w*32 + nt*16 + lr;
    #pragma unroll
    for (int h = 0; h < 4; ++h){
      floatx4 z = {0.f,0.f,0.f,0.f};
      floatx4 dn = __builtin_amdgcn_mfma_f32_16x16x32_bf16(ksf[h],    qf[nt][h], z, 0,0,0);
      floatx4 p0 = __builtin_amdgcn_mfma_f32_16x16x32_bf16(kvf[h][0], qf[nt][h], z, 0,0,0);
      floatx4 p1 = __builtin_amdgcn_mfma_f32_16x16x32_bf16(kvf[h][1], qf[nt][h], z, 0,0,0);
      float inv = 1.f / (dn[0] + 1e-6f);
      short4v o0, o1;
      #pragma unroll
      for (int r = 0; r < 4; ++r){ o0[r] = (short)f2bf(p0[r]*inv); o1[r] = (short)f2bf(p1[r]*inv); }
      int c0 = h*32 + lk*4;
      *(short4v*)(S + n_local*128 + ((((c0 >> 3) ^ (n_local & 7)) << 3) + (c0 & 7))) = o0;
      int c1 = c0 + 16;
      *(short4v*)(S + n_local*128 + ((((c1 >> 3) ^ (n_local & 7)) << 3) + (c1 & 7))) = o1;
    }
  }
  __syncthreads();
  // w_out GEMM 4rt x 4ct
  short8 afr2[4][4];
  #pragma unroll
  for (int rtl = 0; rtl < 4; ++rtl)
    #pragma unroll
    for (int ks = 0; ks < 4; ++ks)
      afr2[rtl][ks] = *(const short8*)(woutb + (size_t)(rg*64 + rtl*16 + lr)*128 + ks*32 + lk*8);
  float gs[4][4], gq[4][4];
  #pragma unroll
  for (int rtl = 0; rtl < 4; ++rtl)
    #pragma unroll
    for (int r = 0; r < 4; ++r){ gs[rtl][r] = 0.f; gq[rtl][r] = 0.f; }
  #pragma unroll
  for (int ctl = 0; ctl < 4; ++ctl){
    int nr = (cg*4 + ctl)*16 + lr;
    short8 bfr[4];
    #pragma unroll
    for (int ks = 0; ks < 4; ++ks)
      bfr[ks] = *(const short8*)(S + nr*128 + (((ks*4 + lk) ^ (nr & 7)) << 3));
    int nn = n0 + nr;
    #pragma unroll
    for (int rtl = 0; rtl < 4; ++rtl){
      floatx4 acc = {0.f,0.f,0.f,0.f};
      #pragma unroll
      for (int ks = 0; ks < 4; ++ks)
        acc = __builtin_amdgcn_mfma_f32_16x16x32_bf16(afr2[rtl][ks], bfr[ks], acc, 0,0,0);
      #pragma unroll
      for (int r = 0; r < 4; ++r){
        float hv = acc[r];
        hb[((size_t)(b*128 + rg*64 + rtl*16 + lk*4 + r)) * HW_ + nn] = f2bf(hv);
        gs[rtl][r] += hv; gq[rtl][r] += hv * hv;
      }
    }
  }
  #pragma unroll
  for (int m = 1; m < 16; m <<= 1)
    #pragma unroll
    for (int rtl = 0; rtl < 4; ++rtl)
      #pragma unroll
      for (int r = 0; r < 4; ++r){ gs[rtl][r] += __shfl_xor(gs[rtl][r], m); gq[rtl][r] += __shfl_xor(gq[rtl][r], m); }
  if (lr == 0){
    #pragma unroll
    for (int rtl = 0; rtl < 4; ++rtl)
      #pragma unroll
      for (int r = 0; r < 4; ++r){
        int c = rg*64 + rtl*16 + lk*4 + r;
        gnS[cg][c][0] = gs[rtl][r];
        gnS[cg][c][1] = gq[rtl][r];
      }
  }
  __syncthreads();
  if (t < 128){
    float a = 0.f, q2 = 0.f;
    #pragma unroll
    for (int cgi = 0; cgi < 4; ++cgi){ a += gnS[cgi][t][0]; q2 += gnS[cgi][t][1]; }
    gn2part[((size_t)blk*128 + t)*2 + 0] = a;
    gn2part[((size_t)blk*128 + t)*2 + 1] = q2;
  }
}

// ---- K5: GN2 stats ----
__global__ __launch_bounds__(64) void k_gn2stats(const float* __restrict__ gn2part,
    float* __restrict__ mean, float* __restrict__ rstd){
  int b = blockIdx.x >> 5, g = blockIdx.x & 31;
  int lane = threadIdx.x;
  float s = 0.f, s2 = 0.f;
  #pragma unroll
  for (int j = 0; j < 4; ++j){
    const float* p = gn2part + (((size_t)(b*64 + lane))*128 + g*4 + j)*2;
    s += p[0]; s2 += p[1];
  }
  #pragma unroll
  for (int o = 32; o; o >>= 1){ s += __shfl_down(s, o); s2 += __shfl_down(s2, o); }
  if (lane == 0){
    float m = s * (1.f/65536.f);
    float var = s2 * (1.f/65536.f) - m*m;
    mean[blockIdx.x] = m; rstd[blockIdx.x] = rsqrtf(var + 1e-5f);
  }
}

// ---- K6: out = GN2(h) + x   (residual from bf16 xT tile via LDS unswizzle) ----
__global__ __launch_bounds__(256) void k_final(const unsigned short* __restrict__ hb,
    const unsigned short* __restrict__ xT, float* __restrict__ out,
    const float* __restrict__ mean, const float* __restrict__ rstd,
    const float* __restrict__ g2w, const float* __restrict__ g2b){
  int blk = blockIdx.x;                        // b*64 + tile
  int b = blk >> 6;
  int n0 = (blk & 63) * 256;
  __shared__ unsigned short XS[32768];
  int t = threadIdx.x;
  const unsigned short* src = xT + ((size_t)blk)*32768;
  for (int it = 0; it < 16; ++it){
    int slot = t + it*256;
    *(short8*)(XS + slot*8) = *(const short8*)(src + slot*8);
  }
  __syncthreads();
  for (int it = 0; it < 16; ++it){
    int idx = t + it*256;                      // 4096 = 128 c x 32 octets
    int c = idx >> 5, oct = idx & 31;
    int bg = b*32 + (c >> 2);
    float m = mean[bg], r = rstd[bg];
    float sc = r * g2w[c], sh = g2b[c] - m * sc;
    size_t gbase = ((size_t)(b*128 + c))*HW_ + n0 + oct*8;
    short8 hv = *(const short8*)(hb + gbase);
    float ov[8];
    #pragma unroll
    for (int j = 0; j < 8; ++j){
      int n = oct*8 + j;
      unsigned short xv = XS[n*128 + ((((c >> 3) ^ keyx(n)) << 3) + (c & 7))];
      ov[j] = bf2f((unsigned short)hv[j])*sc + sh + bf2f(xv);
    }
    float4* op = (float4*)(out + gbase);
    float4 o0, o1;
    o0.x = ov[0]; o0.y = ov[1]; o0.z = ov[2]; o0.w = ov[3];
    o1.x = ov[4]; o1.y = ov[5]; o1.z = ov[6]; o1.w = ov[7];
    op[0] = o0; op[1] = o1;
  }
}

extern "C" void kernel_launch(void* const* d_in, const int* in_sizes, int n_in,
                              void* d_out, int out_size, void* d_ws, size_t ws_size,
                              hipStream_t stream){
  const float* x    = (const float*)d_in[0];
  const float* g1w  = (const float*)d_in[1];
  const float* g1b  = (const float*)d_in[2];
  const float* wqkv = (const float*)d_in[3];
  const float* wout = (const float*)d_in[4];
  const float* g2w  = (const float*)d_in[5];
  const float* g2b  = (const float*)d_in[6];
  char* ws = (char*)d_ws;
  (void)in_sizes; (void)n_in; (void)out_size; (void)ws_size;

  float* gn1part  = (float*)(ws + 0);                        // 256KB
  float* gn1_mean = (float*)(ws + 262144);
  float* gn1_rstd = (float*)(ws + 264192);
  float* gn2_mean = (float*)(ws + 266240);
  float* gn2_rstd = (float*)(ws + 268288);
  float* bias     = (float*)(ws + 270336);                   // 24KB
  unsigned short* woutb = (unsigned short*)(ws + 294912);    // 32KB
  unsigned short* kvF   = (unsigned short*)(ws + 327680);    // 192KB
  unsigned short* wqp   = (unsigned short*)(ws + 524288);    // 1.5MB -> 2097152
  float* ksumpart = (float*)(ws + 2097152);                  // 128KB -> 2228224
  float* kvpart   = (float*)(ws + 2228224);                  // 4MB -> 6422528
  float* gn2part  = (float*)(ws + 6422528);                  // 1MB -> 7471104
  unsigned short* xT = (unsigned short*)(ws + 8388608);      // 64MB -> 75497472
  unsigned short* hb = (unsigned short*)(ws + 75497472);     // 64MB -> 142606336

  k_xprep<<<dim3(1024), dim3(512), 0, stream>>>(x, xT, gn1part);
  k_gn1fin<<<dim3(512), dim3(64), 0, stream>>>(gn1part, gn1_mean, gn1_rstd);
  k_fold<<<dim3(6272), dim3(64), 0, stream>>>(wqkv, wout, g1w, g1b, gn1_mean, gn1_rstd, wqp, bias, woutb);
  k_kv<<<dim3(256), dim3(512), 0, stream>>>(xT, wqp, bias, kvpart, ksumpart);
  k_kvfin<<<dim3(64), dim3(256), 0, stream>>>(kvpart, ksumpart, kvF);
  k_attn2<<<dim3(1024), dim3(512), 0, stream>>>(xT, wqp, bias, kvF, woutb, hb, gn2part);
  k_gn2stats<<<dim3(512), dim3(64), 0, stream>>>(gn2part, gn2_mean, gn2_rstd);
  k_final<<<dim3(1024), dim3(256), 0, stream>>>(hb, xT, (float*)d_out, gn2_mean, gn2_rstd, g2w, g2b);
}